// Round 3
// baseline (527.004 us; speedup 1.0000x reference)
//
#include <hip/hip_runtime.h>
#include <hip/hip_bf16.h>

#define EPSBN 1e-3f

constexpr int kW   = 64;
constexpr int kF   = 120;
constexpr int kC1  = 192;   // 3*W
constexpr int kOut = 121;
constexpr int ROWS = 16;    // rows per block
constexpr int BTOT = 16384;
constexpr int CSTR = 193;   // comb row stride (padded)
constexpr int PSTR = 244;   // P/Q row stride (16B-aligned)

__global__ __launch_bounds__(256) void fused_blink(
    const float* __restrict__ x,
    const float* __restrict__ conv_w, const float* __restrict__ conv_b,
    const float* __restrict__ e_g1, const float* __restrict__ e_b1,
    const float* __restrict__ e_m1, const float* __restrict__ e_v1,
    const float* __restrict__ e_d1_w, const float* __restrict__ e_d1_b,
    const float* __restrict__ e_g2, const float* __restrict__ e_b2,
    const float* __restrict__ e_m2, const float* __restrict__ e_v2,
    const float* __restrict__ e_d2_w, const float* __restrict__ e_d2_b,
    const float* __restrict__ e_d3_w, const float* __restrict__ e_d3_b,
    const float* __restrict__ b_g1, const float* __restrict__ b_b1,
    const float* __restrict__ b_m1, const float* __restrict__ b_v1,
    const float* __restrict__ b_d1_w, const float* __restrict__ b_d1_b,
    const float* __restrict__ b_g2, const float* __restrict__ b_b2,
    const float* __restrict__ b_m2, const float* __restrict__ b_v2,
    const float* __restrict__ b_d2_w, const float* __restrict__ b_d2_b,
    const float* __restrict__ b_d3_w, const float* __restrict__ b_d3_b,
    float* __restrict__ out)
{
  __shared__ float comb[ROWS * CSTR];
  __shared__ __align__(16) float Pb[ROWS * PSTR];
  __shared__ __align__(16) float Qb[ROWS * PSTR];

  const int tid = threadIdx.x;
  const int b0  = blockIdx.x * ROWS;

  // ---------------- Phase 1: per-timestep conv (3 filters) + tanh ----------------
  {
    const int lane = tid & 63;
    const int wid  = tid >> 6;
    const int rloc = lane >> 4;          // 0..3
    const int wloc = lane & 15;          // 0..15
    const int rcv  = wid * 4 + rloc;     // 0..15

    for (int wc = 0; wc < 4; ++wc) {
      const int w = wc * 16 + wloc;
      const float* xr  = x + ((size_t)(b0 + rcv) * kW + w) * kF;
      const float* cwp = conv_w + (size_t)w * 360;   // row: [f*3+k], f<120,k<3
      float a0 = 0.f, a1 = 0.f, a2 = 0.f;
      for (int t = 0; t < 30; ++t) {
        float4 xv = *reinterpret_cast<const float4*>(xr + 4 * t);
        float4 c0 = *reinterpret_cast<const float4*>(cwp + 12 * t);
        float4 c1 = *reinterpret_cast<const float4*>(cwp + 12 * t + 4);
        float4 c2 = *reinterpret_cast<const float4*>(cwp + 12 * t + 8);
        // linear (f*3+k): c0=[f0k0 f0k1 f0k2 f1k0] c1=[f1k1 f1k2 f2k0 f2k1] c2=[f2k2 f3k0 f3k1 f3k2]
        a0 += xv.x * c0.x + xv.y * c0.w + xv.z * c1.z + xv.w * c2.y;
        a1 += xv.x * c0.y + xv.y * c1.x + xv.z * c1.w + xv.w * c2.z;
        a2 += xv.x * c0.z + xv.y * c1.y + xv.z * c2.x + xv.w * c2.w;
      }
      comb[rcv * CSTR + 3 * w + 0] = tanhf(a0 + conv_b[3 * w + 0]);
      comb[rcv * CSTR + 3 * w + 1] = tanhf(a1 + conv_b[3 * w + 1]);
      comb[rcv * CSTR + 3 * w + 2] = tanhf(a2 + conv_b[3 * w + 2]);
    }
  }
  __syncthreads();

  // ---------------- Phase 2: MLP heads ----------------
  // thread = (row r, col-group cg); each dense layer: cols j = cg + 16*c.
  const int r  = tid & 15;
  const int cg = tid >> 4;
  const float* combr = comb + r * CSTR;
  float* Pr = Pb + r * PSTR;
  float* Qr = Qb + r * PSTR;

  // BN_e(comb) -> P
  for (int c = 0; c < 12; ++c) {
    int i = cg + 16 * c;
    float s = e_g1[i] * rsqrtf(e_v1[i] + EPSBN);
    Pr[i] = combr[i] * s + (e_b1[i] - e_m1[i] * s);
  }
  __syncthreads();

  // eye d1: [192]->[192], tanh, BN2 -> Q
  for (int j = cg; j < 192; j += 16) {
    const float* wc_ = e_d1_w + j;
    float acc = e_d1_b[j];
    for (int i = 0; i < 192; ++i) acc = fmaf(Pr[i], wc_[(size_t)i * 192], acc);
    float s = e_g2[j] * rsqrtf(e_v2[j] + EPSBN);
    Qr[j] = tanhf(acc) * s + (e_b2[j] - e_m2[j] * s);
  }
  __syncthreads();

  // eye d2: [192]->[240] -> P
  for (int j = cg; j < 240; j += 16) {
    const float* wc_ = e_d2_w + j;
    float acc = e_d2_b[j];
    for (int i = 0; i < 192; ++i) acc = fmaf(Qr[i], wc_[(size_t)i * 240], acc);
    Pr[j] = acc;
  }
  __syncthreads();

  // BN_b(comb) -> Q  (Q is dead: d2 finished reading it before the barrier)
  for (int c = 0; c < 12; ++c) {
    int i = cg + 16 * c;
    float s = b_g1[i] * rsqrtf(b_v1[i] + EPSBN);
    Qr[i] = combr[i] * s + (b_b1[i] - b_m1[i] * s);
  }
  // eye d3: [240]->[120] -> out (reads P; independent of the Q writes above)
  for (int j = cg; j < 120; j += 16) {
    const float* wc_ = e_d3_w + j;
    float acc = e_d3_b[j];
    for (int i = 0; i < 240; ++i) acc = fmaf(Pr[i], wc_[(size_t)i * 120], acc);
    out[(size_t)(b0 + r) * kOut + j] = acc;
  }
  __syncthreads();

  // blink d1: [192]->[64], tanh, BN2 -> P (reads Q)
  for (int j = cg; j < 64; j += 16) {
    const float* wc_ = b_d1_w + j;
    float acc = b_d1_b[j];
    for (int i = 0; i < 192; ++i) acc = fmaf(Qr[i], wc_[(size_t)i * 64], acc);
    float s = b_g2[j] * rsqrtf(b_v2[j] + EPSBN);
    Pr[j] = tanhf(acc) * s + (b_b2[j] - b_m2[j] * s);
  }
  __syncthreads();

  // blink d2: [64]->[32], tanh -> Q (reads P)
  for (int j = cg; j < 32; j += 16) {
    float acc = b_d2_b[j];
    for (int i = 0; i < 64; ++i) acc = fmaf(Pr[i], b_d2_w[(size_t)i * 32 + j], acc);
    Qr[j] = tanhf(acc);
  }
  __syncthreads();

  // blink d3: [32]->[1], sigmoid -> out col 120
  if (cg == 0) {
    float acc = b_d3_b[0];
    for (int i = 0; i < 32; ++i) acc = fmaf(Qr[i], b_d3_w[i], acc);
    out[(size_t)(b0 + r) * kOut + 120] = 1.f / (1.f + expf(-acc));
  }
}

extern "C" void kernel_launch(void* const* d_in, const int* in_sizes, int n_in,
                              void* d_out, int out_size, void* d_ws, size_t ws_size,
                              hipStream_t stream) {
  (void)in_sizes; (void)n_in; (void)d_ws; (void)ws_size; (void)out_size;
  const float* p[31];
  for (int i = 0; i < 31; ++i) p[i] = (const float*)d_in[i];
  dim3 grid(BTOT / ROWS), block(256);
  hipLaunchKernelGGL(fused_blink, grid, block, 0, stream,
    p[0], p[1], p[2], p[3], p[4], p[5], p[6], p[7], p[8], p[9],
    p[10], p[11], p[12], p[13], p[14], p[15], p[16], p[17], p[18], p[19],
    p[20], p[21], p[22], p[23], p[24], p[25], p[26], p[27], p[28], p[29], p[30],
    (float*)d_out);
}

// Round 4
// 469.372 us; speedup vs baseline: 1.1228x; 1.1228x over previous
//
#include <hip/hip_runtime.h>
#include <hip/hip_bf16.h>

#define EPSBN 1e-3f

constexpr int kW   = 64;
constexpr int kF   = 120;
constexpr int kC1  = 192;   // 3*W
constexpr int kN2  = 240;
constexpr int kOut = 121;
constexpr int ROWS = 16;    // rows per block
constexpr int RPW  = 4;     // rows per wave (phase 2)
constexpr int BTOT = 16384;
constexpr int CSTR = 193;   // comb row stride (padded)

__global__ __launch_bounds__(256) void fused_blink(
    const float* __restrict__ x,
    const float* __restrict__ conv_w, const float* __restrict__ conv_b,
    const float* __restrict__ e_g1, const float* __restrict__ e_b1,
    const float* __restrict__ e_m1, const float* __restrict__ e_v1,
    const float* __restrict__ e_d1_w, const float* __restrict__ e_d1_b,
    const float* __restrict__ e_g2, const float* __restrict__ e_b2,
    const float* __restrict__ e_m2, const float* __restrict__ e_v2,
    const float* __restrict__ e_d2_w, const float* __restrict__ e_d2_b,
    const float* __restrict__ e_d3_w, const float* __restrict__ e_d3_b,
    const float* __restrict__ b_g1, const float* __restrict__ b_b1,
    const float* __restrict__ b_m1, const float* __restrict__ b_v1,
    const float* __restrict__ b_d1_w, const float* __restrict__ b_d1_b,
    const float* __restrict__ b_g2, const float* __restrict__ b_b2,
    const float* __restrict__ b_m2, const float* __restrict__ b_v2,
    const float* __restrict__ b_d2_w, const float* __restrict__ b_d2_b,
    const float* __restrict__ b_d3_w, const float* __restrict__ b_d3_b,
    float* __restrict__ out)
{
  __shared__ float comb[ROWS * CSTR];                      // 12.35 KB
  __shared__ __align__(16) float Ab[ROWS * kN2];           // 15.36 KB
  __shared__ __align__(16) float Bb[ROWS * kN2];           // 15.36 KB

  const int tid  = threadIdx.x;
  const int lane = tid & 63;
  const int wid  = tid >> 6;
  const int b0   = blockIdx.x * ROWS;

  // ---------------- Phase 1: per-timestep conv (3 filters) + tanh ----------------
  // (verbatim from the round-3 passing kernel)
  {
    const int rloc = lane >> 4;          // 0..3
    const int wloc = lane & 15;          // 0..15
    const int rcv  = wid * 4 + rloc;     // 0..15

    for (int wc = 0; wc < 4; ++wc) {
      const int w = wc * 16 + wloc;
      const float* xr  = x + ((size_t)(b0 + rcv) * kW + w) * kF;
      const float* cwp = conv_w + (size_t)w * 360;   // row: [f*3+k], f<120,k<3
      float a0 = 0.f, a1 = 0.f, a2 = 0.f;
      for (int t = 0; t < 30; ++t) {
        float4 xv = *reinterpret_cast<const float4*>(xr + 4 * t);
        float4 c0 = *reinterpret_cast<const float4*>(cwp + 12 * t);
        float4 c1 = *reinterpret_cast<const float4*>(cwp + 12 * t + 4);
        float4 c2 = *reinterpret_cast<const float4*>(cwp + 12 * t + 8);
        a0 += xv.x * c0.x + xv.y * c0.w + xv.z * c1.z + xv.w * c2.y;
        a1 += xv.x * c0.y + xv.y * c1.x + xv.z * c1.w + xv.w * c2.z;
        a2 += xv.x * c0.z + xv.y * c1.y + xv.z * c2.x + xv.w * c2.w;
      }
      comb[rcv * CSTR + 3 * w + 0] = tanhf(a0 + conv_b[3 * w + 0]);
      comb[rcv * CSTR + 3 * w + 1] = tanhf(a1 + conv_b[3 * w + 1]);
      comb[rcv * CSTR + 3 * w + 2] = tanhf(a2 + conv_b[3 * w + 2]);
    }
  }
  __syncthreads();

  // ---------------- Phase 2: MLP heads, 4 rows per wave, lane = column ----------------
  const int r0 = wid * RPW;
  float* A  = Ab;
  float* Bf = Bb;
  #define AR(rr) (A  + (size_t)(r0 + (rr)) * kN2)
  #define BR(rr) (Bf + (size_t)(r0 + (rr)) * kN2)

  // ---- stage BN_e(combined) into A ----
  #pragma unroll
  for (int q = 0; q < 12; ++q) {
    int rr = q >> 2;          // 0..2 -> wait: 12 = 4 rows * 3 col-chunks
    int cc = q & 3;
    // remap: q -> (rr: 0..3, cc: 0..2)
    rr = q / 3; cc = q % 3;
    int i = cc * 64 + lane;
    float s = e_g1[i] * rsqrtf(e_v1[i] + EPSBN);
    AR(rr)[i] = comb[(r0 + rr) * CSTR + i] * s + (e_b1[i] - e_m1[i] * s);
  }
  __syncthreads();

  // ---- eye d1: [192]->[192], tanh, BN2 -> Bf ----
  {
    float acc[RPW][3];
    #pragma unroll
    for (int rr = 0; rr < RPW; ++rr) { acc[rr][0] = acc[rr][1] = acc[rr][2] = 0.f; }
    for (int i = 0; i < kC1; i += 4) {
      float4 v0 = *reinterpret_cast<const float4*>(AR(0) + i);
      float4 v1 = *reinterpret_cast<const float4*>(AR(1) + i);
      float4 v2 = *reinterpret_cast<const float4*>(AR(2) + i);
      float4 v3 = *reinterpret_cast<const float4*>(AR(3) + i);
#define STEP1(cmp, io) { \
      const float* wp = e_d1_w + (size_t)(i + io) * kC1 + lane; \
      float w0 = wp[0], w1 = wp[64], w2 = wp[128]; \
      acc[0][0] = fmaf(v0.cmp, w0, acc[0][0]); acc[0][1] = fmaf(v0.cmp, w1, acc[0][1]); acc[0][2] = fmaf(v0.cmp, w2, acc[0][2]); \
      acc[1][0] = fmaf(v1.cmp, w0, acc[1][0]); acc[1][1] = fmaf(v1.cmp, w1, acc[1][1]); acc[1][2] = fmaf(v1.cmp, w2, acc[1][2]); \
      acc[2][0] = fmaf(v2.cmp, w0, acc[2][0]); acc[2][1] = fmaf(v2.cmp, w1, acc[2][1]); acc[2][2] = fmaf(v2.cmp, w2, acc[2][2]); \
      acc[3][0] = fmaf(v3.cmp, w0, acc[3][0]); acc[3][1] = fmaf(v3.cmp, w1, acc[3][1]); acc[3][2] = fmaf(v3.cmp, w2, acc[3][2]); }
      STEP1(x, 0) STEP1(y, 1) STEP1(z, 2) STEP1(w, 3)
#undef STEP1
    }
    #pragma unroll
    for (int c = 0; c < 3; ++c) {
      int j = c * 64 + lane;
      float s  = e_g2[j] * rsqrtf(e_v2[j] + EPSBN);
      float t  = e_b2[j] - e_m2[j] * s;
      float bs = e_d1_b[j];
      #pragma unroll
      for (int rr = 0; rr < RPW; ++rr)
        BR(rr)[j] = tanhf(acc[rr][c] + bs) * s + t;
    }
  }
  __syncthreads();

  // ---- eye d2: [192]->[240] -> A ----
  {
    const bool m3 = (lane < 48);
    float acc2[RPW][4];
    #pragma unroll
    for (int rr = 0; rr < RPW; ++rr) { acc2[rr][0]=acc2[rr][1]=acc2[rr][2]=acc2[rr][3]=0.f; }
    for (int i = 0; i < kC1; i += 4) {
      float4 v0 = *reinterpret_cast<const float4*>(BR(0) + i);
      float4 v1 = *reinterpret_cast<const float4*>(BR(1) + i);
      float4 v2 = *reinterpret_cast<const float4*>(BR(2) + i);
      float4 v3 = *reinterpret_cast<const float4*>(BR(3) + i);
#define STEP2(cmp, io) { \
      const float* wp = e_d2_w + (size_t)(i + io) * kN2 + lane; \
      float w0 = wp[0], w1 = wp[64], w2 = wp[128]; \
      float w3 = m3 ? wp[192] : 0.f; \
      acc2[0][0] = fmaf(v0.cmp, w0, acc2[0][0]); acc2[0][1] = fmaf(v0.cmp, w1, acc2[0][1]); acc2[0][2] = fmaf(v0.cmp, w2, acc2[0][2]); acc2[0][3] = fmaf(v0.cmp, w3, acc2[0][3]); \
      acc2[1][0] = fmaf(v1.cmp, w0, acc2[1][0]); acc2[1][1] = fmaf(v1.cmp, w1, acc2[1][1]); acc2[1][2] = fmaf(v1.cmp, w2, acc2[1][2]); acc2[1][3] = fmaf(v1.cmp, w3, acc2[1][3]); \
      acc2[2][0] = fmaf(v2.cmp, w0, acc2[2][0]); acc2[2][1] = fmaf(v2.cmp, w1, acc2[2][1]); acc2[2][2] = fmaf(v2.cmp, w2, acc2[2][2]); acc2[2][3] = fmaf(v2.cmp, w3, acc2[2][3]); \
      acc2[3][0] = fmaf(v3.cmp, w0, acc2[3][0]); acc2[3][1] = fmaf(v3.cmp, w1, acc2[3][1]); acc2[3][2] = fmaf(v3.cmp, w2, acc2[3][2]); acc2[3][3] = fmaf(v3.cmp, w3, acc2[3][3]); }
      STEP2(x, 0) STEP2(y, 1) STEP2(z, 2) STEP2(w, 3)
#undef STEP2
    }
    #pragma unroll
    for (int c = 0; c < 4; ++c) {
      int j = c * 64 + lane;
      if (c < 3 || m3) {
        float bs = e_d2_b[j];
        #pragma unroll
        for (int rr = 0; rr < RPW; ++rr)
          AR(rr)[j] = acc2[rr][c] + bs;
      }
    }
  }
  __syncthreads();

  // ---- stage BN_b(combined) into Bf (Bf is dead: d2 consumed it) ----
  #pragma unroll
  for (int q = 0; q < 12; ++q) {
    int rr = q / 3, cc = q % 3;
    int i = cc * 64 + lane;
    float s = b_g1[i] * rsqrtf(b_v1[i] + EPSBN);
    BR(rr)[i] = comb[(r0 + rr) * CSTR + i] * s + (b_b1[i] - b_m1[i] * s);
  }
  // ---- eye d3: [240]->[120] -> out (reads A; independent of Bf writes above) ----
  {
    const bool m56 = (lane < 56);
    float acc3[RPW][2];
    #pragma unroll
    for (int rr = 0; rr < RPW; ++rr) { acc3[rr][0] = acc3[rr][1] = 0.f; }
    for (int i = 0; i < kN2; i += 4) {
      float4 v0 = *reinterpret_cast<const float4*>(AR(0) + i);
      float4 v1 = *reinterpret_cast<const float4*>(AR(1) + i);
      float4 v2 = *reinterpret_cast<const float4*>(AR(2) + i);
      float4 v3 = *reinterpret_cast<const float4*>(AR(3) + i);
#define STEP3(cmp, io) { \
      const float* wp = e_d3_w + (size_t)(i + io) * 120 + lane; \
      float w0 = wp[0]; \
      float w1 = m56 ? wp[64] : 0.f; \
      acc3[0][0] = fmaf(v0.cmp, w0, acc3[0][0]); acc3[0][1] = fmaf(v0.cmp, w1, acc3[0][1]); \
      acc3[1][0] = fmaf(v1.cmp, w0, acc3[1][0]); acc3[1][1] = fmaf(v1.cmp, w1, acc3[1][1]); \
      acc3[2][0] = fmaf(v2.cmp, w0, acc3[2][0]); acc3[2][1] = fmaf(v2.cmp, w1, acc3[2][1]); \
      acc3[3][0] = fmaf(v3.cmp, w0, acc3[3][0]); acc3[3][1] = fmaf(v3.cmp, w1, acc3[3][1]); }
      STEP3(x, 0) STEP3(y, 1) STEP3(z, 2) STEP3(w, 3)
#undef STEP3
    }
    #pragma unroll
    for (int c = 0; c < 2; ++c) {
      int j = c * 64 + lane;
      if (j < 120) {
        float bs = e_d3_b[j];
        #pragma unroll
        for (int rr = 0; rr < RPW; ++rr)
          out[(size_t)(b0 + r0 + rr) * kOut + j] = acc3[rr][c] + bs;
      }
    }
  }
  __syncthreads();

  // ---- blink d1: [192]->[64], tanh, BN2 -> A (reads Bf) ----
  {
    float accb[RPW] = {0.f, 0.f, 0.f, 0.f};
    for (int i = 0; i < kC1; i += 4) {
      float4 v0 = *reinterpret_cast<const float4*>(BR(0) + i);
      float4 v1 = *reinterpret_cast<const float4*>(BR(1) + i);
      float4 v2 = *reinterpret_cast<const float4*>(BR(2) + i);
      float4 v3 = *reinterpret_cast<const float4*>(BR(3) + i);
#define STEPB1(cmp, io) { \
      float w0 = b_d1_w[(size_t)(i + io) * 64 + lane]; \
      accb[0] = fmaf(v0.cmp, w0, accb[0]); accb[1] = fmaf(v1.cmp, w0, accb[1]); \
      accb[2] = fmaf(v2.cmp, w0, accb[2]); accb[3] = fmaf(v3.cmp, w0, accb[3]); }
      STEPB1(x, 0) STEPB1(y, 1) STEPB1(z, 2) STEPB1(w, 3)
#undef STEPB1
    }
    float s  = b_g2[lane] * rsqrtf(b_v2[lane] + EPSBN);
    float t  = b_b2[lane] - b_m2[lane] * s;
    float bs = b_d1_b[lane];
    #pragma unroll
    for (int rr = 0; rr < RPW; ++rr)
      AR(rr)[lane] = tanhf(accb[rr] + bs) * s + t;
  }
  __syncthreads();

  // ---- blink d2: [64]->[32], tanh -> Bf (reads A) ----
  {
    const bool m32 = (lane < 32);
    float accc[RPW] = {0.f, 0.f, 0.f, 0.f};
    for (int i = 0; i < 64; i += 4) {
      float4 v0 = *reinterpret_cast<const float4*>(AR(0) + i);
      float4 v1 = *reinterpret_cast<const float4*>(AR(1) + i);
      float4 v2 = *reinterpret_cast<const float4*>(AR(2) + i);
      float4 v3 = *reinterpret_cast<const float4*>(AR(3) + i);
#define STEPB2(cmp, io) { \
      float w0 = m32 ? b_d2_w[(size_t)(i + io) * 32 + lane] : 0.f; \
      accc[0] = fmaf(v0.cmp, w0, accc[0]); accc[1] = fmaf(v1.cmp, w0, accc[1]); \
      accc[2] = fmaf(v2.cmp, w0, accc[2]); accc[3] = fmaf(v3.cmp, w0, accc[3]); }
      STEPB2(x, 0) STEPB2(y, 1) STEPB2(z, 2) STEPB2(w, 3)
#undef STEPB2
    }
    if (m32) {
      float bs = b_d2_b[lane];
      #pragma unroll
      for (int rr = 0; rr < RPW; ++rr)
        BR(rr)[lane] = tanhf(accc[rr] + bs);
    }
  }
  __syncthreads();

  // ---- blink d3: [32]->[1], sigmoid -> out col 120 ----
  if (lane < RPW) {
    int rr = lane;
    float acc = b_d3_b[0];
    #pragma unroll
    for (int i = 0; i < 32; ++i)
      acc = fmaf(BR(rr)[i], b_d3_w[i], acc);
    out[(size_t)(b0 + r0 + rr) * kOut + 120] = 1.f / (1.f + expf(-acc));
  }
  #undef AR
  #undef BR
}

extern "C" void kernel_launch(void* const* d_in, const int* in_sizes, int n_in,
                              void* d_out, int out_size, void* d_ws, size_t ws_size,
                              hipStream_t stream) {
  (void)in_sizes; (void)n_in; (void)d_ws; (void)ws_size; (void)out_size;
  const float* p[31];
  for (int i = 0; i < 31; ++i) p[i] = (const float*)d_in[i];
  dim3 grid(BTOT / ROWS), block(256);
  hipLaunchKernelGGL(fused_blink, grid, block, 0, stream,
    p[0], p[1], p[2], p[3], p[4], p[5], p[6], p[7], p[8], p[9],
    p[10], p[11], p[12], p[13], p[14], p[15], p[16], p[17], p[18], p[19],
    p[20], p[21], p[22], p[23], p[24], p[25], p[26], p[27], p[28], p[29], p[30],
    (float*)d_out);
}

// Round 5
// 413.612 us; speedup vs baseline: 1.2741x; 1.1348x over previous
//
#include <hip/hip_runtime.h>
#include <hip/hip_bf16.h>

#define EPSBN 1e-3f

constexpr int kW   = 64;
constexpr int kF   = 120;
constexpr int kC1  = 192;   // 3*W
constexpr int kN2  = 240;
constexpr int kOut = 121;
constexpr int ROWS = 4;     // rows per block (= per wave)
constexpr int RPW  = 4;     // rows per wave
constexpr int BTOT = 16384;
constexpr int CSTR = 193;   // comb row stride (padded)

// One wave per block: no cross-wave barriers, every block independent.
// 4096 blocks -> ~14-16 resident waves/CU in different phases overlap
// conv HBM-streaming with MLP L2/VALU work.
__global__ __launch_bounds__(64, 4) void fused_blink(
    const float* __restrict__ x,
    const float* __restrict__ conv_w, const float* __restrict__ conv_b,
    const float* __restrict__ e_g1, const float* __restrict__ e_b1,
    const float* __restrict__ e_m1, const float* __restrict__ e_v1,
    const float* __restrict__ e_d1_w, const float* __restrict__ e_d1_b,
    const float* __restrict__ e_g2, const float* __restrict__ e_b2,
    const float* __restrict__ e_m2, const float* __restrict__ e_v2,
    const float* __restrict__ e_d2_w, const float* __restrict__ e_d2_b,
    const float* __restrict__ e_d3_w, const float* __restrict__ e_d3_b,
    const float* __restrict__ b_g1, const float* __restrict__ b_b1,
    const float* __restrict__ b_m1, const float* __restrict__ b_v1,
    const float* __restrict__ b_d1_w, const float* __restrict__ b_d1_b,
    const float* __restrict__ b_g2, const float* __restrict__ b_b2,
    const float* __restrict__ b_m2, const float* __restrict__ b_v2,
    const float* __restrict__ b_d2_w, const float* __restrict__ b_d2_b,
    const float* __restrict__ b_d3_w, const float* __restrict__ b_d3_b,
    float* __restrict__ out)
{
  __shared__ float comb[ROWS * CSTR];                      // 3.09 KB
  __shared__ __align__(16) float Ab[ROWS * kN2];           // 3.84 KB
  __shared__ __align__(16) float Bb[ROWS * kN2];           // 3.84 KB

  const int lane = threadIdx.x;   // 0..63
  const int b0   = blockIdx.x * ROWS;

  // ---------------- Phase 1: per-timestep conv (3 filters) + tanh ----------------
  {
    const int rcv  = lane >> 4;          // 0..3 (row)
    const int wloc = lane & 15;          // 0..15

    for (int wc = 0; wc < 4; ++wc) {
      const int w = wc * 16 + wloc;
      const float* xr  = x + ((size_t)(b0 + rcv) * kW + w) * kF;
      const float* cwp = conv_w + (size_t)w * 360;   // row: [f*3+k], f<120,k<3
      float a0 = 0.f, a1 = 0.f, a2 = 0.f;
      for (int t = 0; t < 30; ++t) {
        float4 xv = *reinterpret_cast<const float4*>(xr + 4 * t);
        float4 c0 = *reinterpret_cast<const float4*>(cwp + 12 * t);
        float4 c1 = *reinterpret_cast<const float4*>(cwp + 12 * t + 4);
        float4 c2 = *reinterpret_cast<const float4*>(cwp + 12 * t + 8);
        a0 += xv.x * c0.x + xv.y * c0.w + xv.z * c1.z + xv.w * c2.y;
        a1 += xv.x * c0.y + xv.y * c1.x + xv.z * c1.w + xv.w * c2.z;
        a2 += xv.x * c0.z + xv.y * c1.y + xv.z * c2.x + xv.w * c2.w;
      }
      comb[rcv * CSTR + 3 * w + 0] = tanhf(a0 + conv_b[3 * w + 0]);
      comb[rcv * CSTR + 3 * w + 1] = tanhf(a1 + conv_b[3 * w + 1]);
      comb[rcv * CSTR + 3 * w + 2] = tanhf(a2 + conv_b[3 * w + 2]);
    }
  }
  __syncthreads();   // single wave: compiles to waitcnt only

  // ---------------- Phase 2: MLP heads, this wave owns rows 0..3 ----------------
  #define AR(rr) (Ab + (size_t)(rr) * kN2)
  #define BR(rr) (Bb + (size_t)(rr) * kN2)

  // ---- stage BN_e(combined) into A ----
  #pragma unroll
  for (int q = 0; q < 12; ++q) {
    int rr = q / 3, cc = q % 3;
    int i = cc * 64 + lane;
    float s = e_g1[i] * rsqrtf(e_v1[i] + EPSBN);
    AR(rr)[i] = comb[rr * CSTR + i] * s + (e_b1[i] - e_m1[i] * s);
  }
  __syncthreads();

  // ---- eye d1: [192]->[192], tanh, BN2 -> Bf ----
  {
    float acc[RPW][3];
    #pragma unroll
    for (int rr = 0; rr < RPW; ++rr) { acc[rr][0] = acc[rr][1] = acc[rr][2] = 0.f; }
    for (int i = 0; i < kC1; i += 4) {
      float4 v0 = *reinterpret_cast<const float4*>(AR(0) + i);
      float4 v1 = *reinterpret_cast<const float4*>(AR(1) + i);
      float4 v2 = *reinterpret_cast<const float4*>(AR(2) + i);
      float4 v3 = *reinterpret_cast<const float4*>(AR(3) + i);
#define STEP1(cmp, io) { \
      const float* wp = e_d1_w + (size_t)(i + io) * kC1 + lane; \
      float w0 = wp[0], w1 = wp[64], w2 = wp[128]; \
      acc[0][0] = fmaf(v0.cmp, w0, acc[0][0]); acc[0][1] = fmaf(v0.cmp, w1, acc[0][1]); acc[0][2] = fmaf(v0.cmp, w2, acc[0][2]); \
      acc[1][0] = fmaf(v1.cmp, w0, acc[1][0]); acc[1][1] = fmaf(v1.cmp, w1, acc[1][1]); acc[1][2] = fmaf(v1.cmp, w2, acc[1][2]); \
      acc[2][0] = fmaf(v2.cmp, w0, acc[2][0]); acc[2][1] = fmaf(v2.cmp, w1, acc[2][1]); acc[2][2] = fmaf(v2.cmp, w2, acc[2][2]); \
      acc[3][0] = fmaf(v3.cmp, w0, acc[3][0]); acc[3][1] = fmaf(v3.cmp, w1, acc[3][1]); acc[3][2] = fmaf(v3.cmp, w2, acc[3][2]); }
      STEP1(x, 0) STEP1(y, 1) STEP1(z, 2) STEP1(w, 3)
#undef STEP1
    }
    #pragma unroll
    for (int c = 0; c < 3; ++c) {
      int j = c * 64 + lane;
      float s  = e_g2[j] * rsqrtf(e_v2[j] + EPSBN);
      float t  = e_b2[j] - e_m2[j] * s;
      float bs = e_d1_b[j];
      #pragma unroll
      for (int rr = 0; rr < RPW; ++rr)
        BR(rr)[j] = tanhf(acc[rr][c] + bs) * s + t;
    }
  }
  __syncthreads();

  // ---- eye d2: [192]->[240] -> A ----
  {
    const bool m3 = (lane < 48);
    float acc2[RPW][4];
    #pragma unroll
    for (int rr = 0; rr < RPW; ++rr) { acc2[rr][0]=acc2[rr][1]=acc2[rr][2]=acc2[rr][3]=0.f; }
    for (int i = 0; i < kC1; i += 4) {
      float4 v0 = *reinterpret_cast<const float4*>(BR(0) + i);
      float4 v1 = *reinterpret_cast<const float4*>(BR(1) + i);
      float4 v2 = *reinterpret_cast<const float4*>(BR(2) + i);
      float4 v3 = *reinterpret_cast<const float4*>(BR(3) + i);
#define STEP2(cmp, io) { \
      const float* wp = e_d2_w + (size_t)(i + io) * kN2 + lane; \
      float w0 = wp[0], w1 = wp[64], w2 = wp[128]; \
      float w3 = m3 ? wp[192] : 0.f; \
      acc2[0][0] = fmaf(v0.cmp, w0, acc2[0][0]); acc2[0][1] = fmaf(v0.cmp, w1, acc2[0][1]); acc2[0][2] = fmaf(v0.cmp, w2, acc2[0][2]); acc2[0][3] = fmaf(v0.cmp, w3, acc2[0][3]); \
      acc2[1][0] = fmaf(v1.cmp, w0, acc2[1][0]); acc2[1][1] = fmaf(v1.cmp, w1, acc2[1][1]); acc2[1][2] = fmaf(v1.cmp, w2, acc2[1][2]); acc2[1][3] = fmaf(v1.cmp, w3, acc2[1][3]); \
      acc2[2][0] = fmaf(v2.cmp, w0, acc2[2][0]); acc2[2][1] = fmaf(v2.cmp, w1, acc2[2][1]); acc2[2][2] = fmaf(v2.cmp, w2, acc2[2][2]); acc2[2][3] = fmaf(v2.cmp, w3, acc2[2][3]); \
      acc2[3][0] = fmaf(v3.cmp, w0, acc2[3][0]); acc2[3][1] = fmaf(v3.cmp, w1, acc2[3][1]); acc2[3][2] = fmaf(v3.cmp, w2, acc2[3][2]); acc2[3][3] = fmaf(v3.cmp, w3, acc2[3][3]); }
      STEP2(x, 0) STEP2(y, 1) STEP2(z, 2) STEP2(w, 3)
#undef STEP2
    }
    #pragma unroll
    for (int c = 0; c < 4; ++c) {
      int j = c * 64 + lane;
      if (c < 3 || m3) {
        float bs = e_d2_b[j];
        #pragma unroll
        for (int rr = 0; rr < RPW; ++rr)
          AR(rr)[j] = acc2[rr][c] + bs;
      }
    }
  }
  __syncthreads();

  // ---- stage BN_b(combined) into Bf (Bf dead: d2 consumed it) ----
  #pragma unroll
  for (int q = 0; q < 12; ++q) {
    int rr = q / 3, cc = q % 3;
    int i = cc * 64 + lane;
    float s = b_g1[i] * rsqrtf(b_v1[i] + EPSBN);
    BR(rr)[i] = comb[rr * CSTR + i] * s + (b_b1[i] - b_m1[i] * s);
  }
  // ---- eye d3: [240]->[120] -> out (reads A) ----
  {
    const bool m56 = (lane < 56);
    float acc3[RPW][2];
    #pragma unroll
    for (int rr = 0; rr < RPW; ++rr) { acc3[rr][0] = acc3[rr][1] = 0.f; }
    for (int i = 0; i < kN2; i += 4) {
      float4 v0 = *reinterpret_cast<const float4*>(AR(0) + i);
      float4 v1 = *reinterpret_cast<const float4*>(AR(1) + i);
      float4 v2 = *reinterpret_cast<const float4*>(AR(2) + i);
      float4 v3 = *reinterpret_cast<const float4*>(AR(3) + i);
#define STEP3(cmp, io) { \
      const float* wp = e_d3_w + (size_t)(i + io) * 120 + lane; \
      float w0 = wp[0]; \
      float w1 = m56 ? wp[64] : 0.f; \
      acc3[0][0] = fmaf(v0.cmp, w0, acc3[0][0]); acc3[0][1] = fmaf(v0.cmp, w1, acc3[0][1]); \
      acc3[1][0] = fmaf(v1.cmp, w0, acc3[1][0]); acc3[1][1] = fmaf(v1.cmp, w1, acc3[1][1]); \
      acc3[2][0] = fmaf(v2.cmp, w0, acc3[2][0]); acc3[2][1] = fmaf(v2.cmp, w1, acc3[2][1]); \
      acc3[3][0] = fmaf(v3.cmp, w0, acc3[3][0]); acc3[3][1] = fmaf(v3.cmp, w1, acc3[3][1]); }
      STEP3(x, 0) STEP3(y, 1) STEP3(z, 2) STEP3(w, 3)
#undef STEP3
    }
    #pragma unroll
    for (int c = 0; c < 2; ++c) {
      int j = c * 64 + lane;
      if (j < 120) {
        float bs = e_d3_b[j];
        #pragma unroll
        for (int rr = 0; rr < RPW; ++rr)
          out[(size_t)(b0 + rr) * kOut + j] = acc3[rr][c] + bs;
      }
    }
  }
  __syncthreads();

  // ---- blink d1: [192]->[64], tanh, BN2 -> A (reads Bf) ----
  {
    float accb[RPW] = {0.f, 0.f, 0.f, 0.f};
    for (int i = 0; i < kC1; i += 4) {
      float4 v0 = *reinterpret_cast<const float4*>(BR(0) + i);
      float4 v1 = *reinterpret_cast<const float4*>(BR(1) + i);
      float4 v2 = *reinterpret_cast<const float4*>(BR(2) + i);
      float4 v3 = *reinterpret_cast<const float4*>(BR(3) + i);
#define STEPB1(cmp, io) { \
      float w0 = b_d1_w[(size_t)(i + io) * 64 + lane]; \
      accb[0] = fmaf(v0.cmp, w0, accb[0]); accb[1] = fmaf(v1.cmp, w0, accb[1]); \
      accb[2] = fmaf(v2.cmp, w0, accb[2]); accb[3] = fmaf(v3.cmp, w0, accb[3]); }
      STEPB1(x, 0) STEPB1(y, 1) STEPB1(z, 2) STEPB1(w, 3)
#undef STEPB1
    }
    float s  = b_g2[lane] * rsqrtf(b_v2[lane] + EPSBN);
    float t  = b_b2[lane] - b_m2[lane] * s;
    float bs = b_d1_b[lane];
    #pragma unroll
    for (int rr = 0; rr < RPW; ++rr)
      AR(rr)[lane] = tanhf(accb[rr] + bs) * s + t;
  }
  __syncthreads();

  // ---- blink d2: [64]->[32], tanh -> Bf (reads A) ----
  {
    const bool m32 = (lane < 32);
    float accc[RPW] = {0.f, 0.f, 0.f, 0.f};
    for (int i = 0; i < 64; i += 4) {
      float4 v0 = *reinterpret_cast<const float4*>(AR(0) + i);
      float4 v1 = *reinterpret_cast<const float4*>(AR(1) + i);
      float4 v2 = *reinterpret_cast<const float4*>(AR(2) + i);
      float4 v3 = *reinterpret_cast<const float4*>(AR(3) + i);
#define STEPB2(cmp, io) { \
      float w0 = m32 ? b_d2_w[(size_t)(i + io) * 32 + lane] : 0.f; \
      accc[0] = fmaf(v0.cmp, w0, accc[0]); accc[1] = fmaf(v1.cmp, w0, accc[1]); \
      accc[2] = fmaf(v2.cmp, w0, accc[2]); accc[3] = fmaf(v3.cmp, w0, accc[3]); }
      STEPB2(x, 0) STEPB2(y, 1) STEPB2(z, 2) STEPB2(w, 3)
#undef STEPB2
    }
    if (m32) {
      float bs = b_d2_b[lane];
      #pragma unroll
      for (int rr = 0; rr < RPW; ++rr)
        BR(rr)[lane] = tanhf(accc[rr] + bs);
    }
  }
  __syncthreads();

  // ---- blink d3: [32]->[1], sigmoid -> out col 120 ----
  if (lane < RPW) {
    int rr = lane;
    float acc = b_d3_b[0];
    #pragma unroll
    for (int i = 0; i < 32; ++i)
      acc = fmaf(BR(rr)[i], b_d3_w[i], acc);
    out[(size_t)(b0 + rr) * kOut + 120] = 1.f / (1.f + expf(-acc));
  }
  #undef AR
  #undef BR
}

extern "C" void kernel_launch(void* const* d_in, const int* in_sizes, int n_in,
                              void* d_out, int out_size, void* d_ws, size_t ws_size,
                              hipStream_t stream) {
  (void)in_sizes; (void)n_in; (void)d_ws; (void)ws_size; (void)out_size;
  const float* p[31];
  for (int i = 0; i < 31; ++i) p[i] = (const float*)d_in[i];
  dim3 grid(BTOT / ROWS), block(64);
  hipLaunchKernelGGL(fused_blink, grid, block, 0, stream,
    p[0], p[1], p[2], p[3], p[4], p[5], p[6], p[7], p[8], p[9],
    p[10], p[11], p[12], p[13], p[14], p[15], p[16], p[17], p[18], p[19],
    p[20], p[21], p[22], p[23], p[24], p[25], p[26], p[27], p[28], p[29], p[30],
    (float*)d_out);
}

// Round 6
// 380.069 us; speedup vs baseline: 1.3866x; 1.0883x over previous
//
#include <hip/hip_runtime.h>
#include <hip/hip_bf16.h>

#define EPSBN 1e-3f

constexpr int kW   = 64;
constexpr int kF   = 120;
constexpr int kC1  = 192;   // 3*W
constexpr int kN2  = 240;
constexpr int kOut = 121;
constexpr int BTOT = 16384;

// ======================= Kernel A: conv + tanh -> combined =======================
// 256 thr = 4 waves x 4 rows; grid 1024 (16 rows/block). Low VGPR, 12 KB LDS ->
// ~16 waves/CU streaming x from HBM. Writes combined[row][192] coalesced.
__global__ __launch_bounds__(256, 4) void conv_kernel(
    const float* __restrict__ x,
    const float* __restrict__ conv_w, const float* __restrict__ conv_b,
    float* __restrict__ combined)
{
  __shared__ float comb[16 * kC1];   // 12.3 KB, unpadded (coalesced dump)

  const int tid  = threadIdx.x;
  const int lane = tid & 63;
  const int wid  = tid >> 6;
  const int b0   = blockIdx.x * 16;

  const int row  = wid * 4 + (lane >> 4);   // 0..15
  const int wloc = lane & 15;

  for (int wc = 0; wc < 4; ++wc) {
    const int w = wc * 16 + wloc;
    const float* xr  = x + ((size_t)(b0 + row) * kW + w) * kF;
    const float* cwp = conv_w + (size_t)w * 360;   // [f*3+k]
    float a0 = 0.f, a1 = 0.f, a2 = 0.f;
    for (int t = 0; t < 30; ++t) {
      float4 xv = *reinterpret_cast<const float4*>(xr + 4 * t);
      float4 c0 = *reinterpret_cast<const float4*>(cwp + 12 * t);
      float4 c1 = *reinterpret_cast<const float4*>(cwp + 12 * t + 4);
      float4 c2 = *reinterpret_cast<const float4*>(cwp + 12 * t + 8);
      a0 += xv.x * c0.x + xv.y * c0.w + xv.z * c1.z + xv.w * c2.y;
      a1 += xv.x * c0.y + xv.y * c1.x + xv.z * c1.w + xv.w * c2.z;
      a2 += xv.x * c0.z + xv.y * c1.y + xv.z * c2.x + xv.w * c2.w;
    }
    comb[row * kC1 + 3 * w + 0] = tanhf(a0 + conv_b[3 * w + 0]);
    comb[row * kC1 + 3 * w + 1] = tanhf(a1 + conv_b[3 * w + 1]);
    comb[row * kC1 + 3 * w + 2] = tanhf(a2 + conv_b[3 * w + 2]);
  }
  __syncthreads();

  // coalesced dump: 16*192 floats = 768 float4; 3 per thread
  float4* dst = reinterpret_cast<float4*>(combined + (size_t)b0 * kC1);
  const float4* srcv = reinterpret_cast<const float4*>(comb);
  #pragma unroll
  for (int q = 0; q < 3; ++q) {
    int idx = q * 256 + tid;
    dst[idx] = srcv[idx];
  }
}

// ======================= Kernel B: MLP heads =======================
// 256 thr = 4 independent waves x 8 rows = 32 rows/block; grid 512 (2 blocks/CU,
// LDS-bound). No __syncthreads: each wave owns its LDS slice. 8-row register
// blocking: every coalesced weight load feeds 8 FMAs.
__global__ __launch_bounds__(256, 2) void mlp_kernel(
    const float* __restrict__ combined,
    const float* __restrict__ e_g1, const float* __restrict__ e_b1,
    const float* __restrict__ e_m1, const float* __restrict__ e_v1,
    const float* __restrict__ e_d1_w, const float* __restrict__ e_d1_b,
    const float* __restrict__ e_g2, const float* __restrict__ e_b2,
    const float* __restrict__ e_m2, const float* __restrict__ e_v2,
    const float* __restrict__ e_d2_w, const float* __restrict__ e_d2_b,
    const float* __restrict__ e_d3_w, const float* __restrict__ e_d3_b,
    const float* __restrict__ b_g1, const float* __restrict__ b_b1,
    const float* __restrict__ b_m1, const float* __restrict__ b_v1,
    const float* __restrict__ b_d1_w, const float* __restrict__ b_d1_b,
    const float* __restrict__ b_g2, const float* __restrict__ b_b2,
    const float* __restrict__ b_m2, const float* __restrict__ b_v2,
    const float* __restrict__ b_d2_w, const float* __restrict__ b_d2_b,
    const float* __restrict__ b_d3_w, const float* __restrict__ b_d3_b,
    float* __restrict__ out)
{
  __shared__ __align__(16) float Ab[32 * kN2];   // 30.7 KB
  __shared__ __align__(16) float Bb[32 * kN2];   // 30.7 KB

  const int tid  = threadIdx.x;
  const int lane = tid & 63;
  const int wid  = tid >> 6;
  const int r0g  = blockIdx.x * 32 + wid * 8;    // this wave's global row base

  float* A0 = Ab + (size_t)wid * 8 * kN2;
  float* B0 = Bb + (size_t)wid * 8 * kN2;
  #define AR(rr) (A0 + (size_t)(rr) * kN2)
  #define BR(rr) (B0 + (size_t)(rr) * kN2)

  // ---- stage BN_e(combined) -> A ----
  #pragma unroll
  for (int cc = 0; cc < 3; ++cc) {
    int i = cc * 64 + lane;
    float s = e_g1[i] * rsqrtf(e_v1[i] + EPSBN);
    float t = e_b1[i] - e_m1[i] * s;
    #pragma unroll
    for (int rr = 0; rr < 8; ++rr)
      AR(rr)[i] = combined[(size_t)(r0g + rr) * kC1 + i] * s + t;
  }

  // ---- eye d1: [192]->[192], tanh, BN2 -> B ----
  {
    float acc[8][3];
    #pragma unroll
    for (int rr = 0; rr < 8; ++rr) { acc[rr][0] = acc[rr][1] = acc[rr][2] = 0.f; }
    for (int i = 0; i < kC1; i += 4) {
      float4 v[8];
      #pragma unroll
      for (int rr = 0; rr < 8; ++rr) v[rr] = *reinterpret_cast<const float4*>(AR(rr) + i);
      #pragma unroll
      for (int io = 0; io < 4; ++io) {
        const float* wp = e_d1_w + (size_t)(i + io) * kC1 + lane;
        float w0 = wp[0], w1 = wp[64], w2 = wp[128];
        #pragma unroll
        for (int rr = 0; rr < 8; ++rr) {
          float xv = reinterpret_cast<const float*>(&v[rr])[io];
          acc[rr][0] = fmaf(xv, w0, acc[rr][0]);
          acc[rr][1] = fmaf(xv, w1, acc[rr][1]);
          acc[rr][2] = fmaf(xv, w2, acc[rr][2]);
        }
      }
    }
    #pragma unroll
    for (int c = 0; c < 3; ++c) {
      int j = c * 64 + lane;
      float s  = e_g2[j] * rsqrtf(e_v2[j] + EPSBN);
      float t  = e_b2[j] - e_m2[j] * s;
      float bs = e_d1_b[j];
      #pragma unroll
      for (int rr = 0; rr < 8; ++rr)
        BR(rr)[j] = tanhf(acc[rr][c] + bs) * s + t;
    }
  }

  // ---- eye d2: [192]->[240] -> A ----
  {
    const bool m3 = (lane < 48);
    float acc[8][4];
    #pragma unroll
    for (int rr = 0; rr < 8; ++rr) { acc[rr][0]=acc[rr][1]=acc[rr][2]=acc[rr][3]=0.f; }
    for (int i = 0; i < kC1; i += 4) {
      float4 v[8];
      #pragma unroll
      for (int rr = 0; rr < 8; ++rr) v[rr] = *reinterpret_cast<const float4*>(BR(rr) + i);
      #pragma unroll
      for (int io = 0; io < 4; ++io) {
        const float* wp = e_d2_w + (size_t)(i + io) * kN2 + lane;
        float w0 = wp[0], w1 = wp[64], w2 = wp[128];
        float w3 = m3 ? wp[192] : 0.f;
        #pragma unroll
        for (int rr = 0; rr < 8; ++rr) {
          float xv = reinterpret_cast<const float*>(&v[rr])[io];
          acc[rr][0] = fmaf(xv, w0, acc[rr][0]);
          acc[rr][1] = fmaf(xv, w1, acc[rr][1]);
          acc[rr][2] = fmaf(xv, w2, acc[rr][2]);
          acc[rr][3] = fmaf(xv, w3, acc[rr][3]);
        }
      }
    }
    #pragma unroll
    for (int c = 0; c < 4; ++c) {
      int j = c * 64 + lane;
      if (c < 3 || m3) {
        float bs = e_d2_b[j];
        #pragma unroll
        for (int rr = 0; rr < 8; ++rr)
          AR(rr)[j] = acc[rr][c] + bs;
      }
    }
  }

  // ---- stage BN_b(combined) -> B (B consumed by d2 already; same-wave order) ----
  #pragma unroll
  for (int cc = 0; cc < 3; ++cc) {
    int i = cc * 64 + lane;
    float s = b_g1[i] * rsqrtf(b_v1[i] + EPSBN);
    float t = b_b1[i] - b_m1[i] * s;
    #pragma unroll
    for (int rr = 0; rr < 8; ++rr)
      BR(rr)[i] = combined[(size_t)(r0g + rr) * kC1 + i] * s + t;
  }

  // ---- eye d3: [240]->[120] -> out ----
  {
    const bool m56 = (lane < 56);
    float acc[8][2];
    #pragma unroll
    for (int rr = 0; rr < 8; ++rr) { acc[rr][0] = acc[rr][1] = 0.f; }
    for (int i = 0; i < kN2; i += 4) {
      float4 v[8];
      #pragma unroll
      for (int rr = 0; rr < 8; ++rr) v[rr] = *reinterpret_cast<const float4*>(AR(rr) + i);
      #pragma unroll
      for (int io = 0; io < 4; ++io) {
        const float* wp = e_d3_w + (size_t)(i + io) * 120 + lane;
        float w0 = wp[0];
        float w1 = m56 ? wp[64] : 0.f;
        #pragma unroll
        for (int rr = 0; rr < 8; ++rr) {
          float xv = reinterpret_cast<const float*>(&v[rr])[io];
          acc[rr][0] = fmaf(xv, w0, acc[rr][0]);
          acc[rr][1] = fmaf(xv, w1, acc[rr][1]);
        }
      }
    }
    #pragma unroll
    for (int c = 0; c < 2; ++c) {
      int j = c * 64 + lane;
      if (j < 120) {
        float bs = e_d3_b[j];
        #pragma unroll
        for (int rr = 0; rr < 8; ++rr)
          out[(size_t)(r0g + rr) * kOut + j] = acc[rr][c] + bs;
      }
    }
  }

  // ---- blink d1: [192]->[64], tanh, BN2 -> A (reads B) ----
  {
    float acc[8];
    #pragma unroll
    for (int rr = 0; rr < 8; ++rr) acc[rr] = 0.f;
    for (int i = 0; i < kC1; i += 4) {
      float4 v[8];
      #pragma unroll
      for (int rr = 0; rr < 8; ++rr) v[rr] = *reinterpret_cast<const float4*>(BR(rr) + i);
      #pragma unroll
      for (int io = 0; io < 4; ++io) {
        float w0 = b_d1_w[(size_t)(i + io) * 64 + lane];
        #pragma unroll
        for (int rr = 0; rr < 8; ++rr) {
          float xv = reinterpret_cast<const float*>(&v[rr])[io];
          acc[rr] = fmaf(xv, w0, acc[rr]);
        }
      }
    }
    float s  = b_g2[lane] * rsqrtf(b_v2[lane] + EPSBN);
    float t  = b_b2[lane] - b_m2[lane] * s;
    float bs = b_d1_b[lane];
    #pragma unroll
    for (int rr = 0; rr < 8; ++rr)
      AR(rr)[lane] = tanhf(acc[rr] + bs) * s + t;
  }

  // ---- blink d2: [64]->[32], tanh -> B (reads A) ----
  {
    const bool m32 = (lane < 32);
    float acc[8];
    #pragma unroll
    for (int rr = 0; rr < 8; ++rr) acc[rr] = 0.f;
    for (int i = 0; i < 64; i += 4) {
      float4 v[8];
      #pragma unroll
      for (int rr = 0; rr < 8; ++rr) v[rr] = *reinterpret_cast<const float4*>(AR(rr) + i);
      #pragma unroll
      for (int io = 0; io < 4; ++io) {
        float w0 = m32 ? b_d2_w[(size_t)(i + io) * 32 + lane] : 0.f;
        #pragma unroll
        for (int rr = 0; rr < 8; ++rr) {
          float xv = reinterpret_cast<const float*>(&v[rr])[io];
          acc[rr] = fmaf(xv, w0, acc[rr]);
        }
      }
    }
    if (m32) {
      float bs = b_d2_b[lane];
      #pragma unroll
      for (int rr = 0; rr < 8; ++rr)
        BR(rr)[lane] = tanhf(acc[rr] + bs);
    }
  }

  // ---- blink d3: [32]->[1], sigmoid -> out col 120 ----
  if (lane < 8) {
    int rr = lane;
    float acc = b_d3_b[0];
    #pragma unroll
    for (int i = 0; i < 32; ++i)
      acc = fmaf(BR(rr)[i], b_d3_w[i], acc);
    out[(size_t)(r0g + rr) * kOut + 120] = 1.f / (1.f + expf(-acc));
  }
  #undef AR
  #undef BR
}

// ======================= Fallback: round-5 fused kernel (known-correct) =======================
constexpr int CSTR = 193;
__global__ __launch_bounds__(64, 4) void fused_blink_fb(
    const float* __restrict__ x,
    const float* __restrict__ conv_w, const float* __restrict__ conv_b,
    const float* __restrict__ e_g1, const float* __restrict__ e_b1,
    const float* __restrict__ e_m1, const float* __restrict__ e_v1,
    const float* __restrict__ e_d1_w, const float* __restrict__ e_d1_b,
    const float* __restrict__ e_g2, const float* __restrict__ e_b2,
    const float* __restrict__ e_m2, const float* __restrict__ e_v2,
    const float* __restrict__ e_d2_w, const float* __restrict__ e_d2_b,
    const float* __restrict__ e_d3_w, const float* __restrict__ e_d3_b,
    const float* __restrict__ b_g1, const float* __restrict__ b_b1,
    const float* __restrict__ b_m1, const float* __restrict__ b_v1,
    const float* __restrict__ b_d1_w, const float* __restrict__ b_d1_b,
    const float* __restrict__ b_g2, const float* __restrict__ b_b2,
    const float* __restrict__ b_m2, const float* __restrict__ b_v2,
    const float* __restrict__ b_d2_w, const float* __restrict__ b_d2_b,
    const float* __restrict__ b_d3_w, const float* __restrict__ b_d3_b,
    float* __restrict__ out)
{
  __shared__ float comb[4 * CSTR];
  __shared__ __align__(16) float Ab[4 * kN2];
  __shared__ __align__(16) float Bb[4 * kN2];
  const int lane = threadIdx.x;
  const int b0   = blockIdx.x * 4;
  {
    const int rcv = lane >> 4, wloc = lane & 15;
    for (int wc = 0; wc < 4; ++wc) {
      const int w = wc * 16 + wloc;
      const float* xr  = x + ((size_t)(b0 + rcv) * kW + w) * kF;
      const float* cwp = conv_w + (size_t)w * 360;
      float a0 = 0.f, a1 = 0.f, a2 = 0.f;
      for (int t = 0; t < 30; ++t) {
        float4 xv = *reinterpret_cast<const float4*>(xr + 4 * t);
        float4 c0 = *reinterpret_cast<const float4*>(cwp + 12 * t);
        float4 c1 = *reinterpret_cast<const float4*>(cwp + 12 * t + 4);
        float4 c2 = *reinterpret_cast<const float4*>(cwp + 12 * t + 8);
        a0 += xv.x * c0.x + xv.y * c0.w + xv.z * c1.z + xv.w * c2.y;
        a1 += xv.x * c0.y + xv.y * c1.x + xv.z * c1.w + xv.w * c2.z;
        a2 += xv.x * c0.z + xv.y * c1.y + xv.z * c2.x + xv.w * c2.w;
      }
      comb[rcv * CSTR + 3 * w + 0] = tanhf(a0 + conv_b[3 * w + 0]);
      comb[rcv * CSTR + 3 * w + 1] = tanhf(a1 + conv_b[3 * w + 1]);
      comb[rcv * CSTR + 3 * w + 2] = tanhf(a2 + conv_b[3 * w + 2]);
    }
  }
  __syncthreads();
  #define AR(rr) (Ab + (size_t)(rr) * kN2)
  #define BR(rr) (Bb + (size_t)(rr) * kN2)
  #pragma unroll
  for (int q = 0; q < 12; ++q) {
    int rr = q / 3, cc = q % 3;
    int i = cc * 64 + lane;
    float s = e_g1[i] * rsqrtf(e_v1[i] + EPSBN);
    AR(rr)[i] = comb[rr * CSTR + i] * s + (e_b1[i] - e_m1[i] * s);
  }
  __syncthreads();
  {
    float acc[4][3];
    #pragma unroll
    for (int rr = 0; rr < 4; ++rr) { acc[rr][0]=acc[rr][1]=acc[rr][2]=0.f; }
    for (int i = 0; i < kC1; i += 4) {
      float4 v[4];
      #pragma unroll
      for (int rr = 0; rr < 4; ++rr) v[rr] = *reinterpret_cast<const float4*>(AR(rr) + i);
      #pragma unroll
      for (int io = 0; io < 4; ++io) {
        const float* wp = e_d1_w + (size_t)(i + io) * kC1 + lane;
        float w0 = wp[0], w1 = wp[64], w2 = wp[128];
        #pragma unroll
        for (int rr = 0; rr < 4; ++rr) {
          float xv = reinterpret_cast<const float*>(&v[rr])[io];
          acc[rr][0] = fmaf(xv, w0, acc[rr][0]);
          acc[rr][1] = fmaf(xv, w1, acc[rr][1]);
          acc[rr][2] = fmaf(xv, w2, acc[rr][2]);
        }
      }
    }
    #pragma unroll
    for (int c = 0; c < 3; ++c) {
      int j = c * 64 + lane;
      float s  = e_g2[j] * rsqrtf(e_v2[j] + EPSBN);
      float t  = e_b2[j] - e_m2[j] * s;
      float bs = e_d1_b[j];
      #pragma unroll
      for (int rr = 0; rr < 4; ++rr)
        BR(rr)[j] = tanhf(acc[rr][c] + bs) * s + t;
    }
  }
  __syncthreads();
  {
    const bool m3 = (lane < 48);
    float acc[4][4];
    #pragma unroll
    for (int rr = 0; rr < 4; ++rr) { acc[rr][0]=acc[rr][1]=acc[rr][2]=acc[rr][3]=0.f; }
    for (int i = 0; i < kC1; i += 4) {
      float4 v[4];
      #pragma unroll
      for (int rr = 0; rr < 4; ++rr) v[rr] = *reinterpret_cast<const float4*>(BR(rr) + i);
      #pragma unroll
      for (int io = 0; io < 4; ++io) {
        const float* wp = e_d2_w + (size_t)(i + io) * kN2 + lane;
        float w0 = wp[0], w1 = wp[64], w2 = wp[128];
        float w3 = m3 ? wp[192] : 0.f;
        #pragma unroll
        for (int rr = 0; rr < 4; ++rr) {
          float xv = reinterpret_cast<const float*>(&v[rr])[io];
          acc[rr][0] = fmaf(xv, w0, acc[rr][0]);
          acc[rr][1] = fmaf(xv, w1, acc[rr][1]);
          acc[rr][2] = fmaf(xv, w2, acc[rr][2]);
          acc[rr][3] = fmaf(xv, w3, acc[rr][3]);
        }
      }
    }
    #pragma unroll
    for (int c = 0; c < 4; ++c) {
      int j = c * 64 + lane;
      if (c < 3 || m3) {
        float bs = e_d2_b[j];
        #pragma unroll
        for (int rr = 0; rr < 4; ++rr)
          AR(rr)[j] = acc[rr][c] + bs;
      }
    }
  }
  __syncthreads();
  #pragma unroll
  for (int q = 0; q < 12; ++q) {
    int rr = q / 3, cc = q % 3;
    int i = cc * 64 + lane;
    float s = b_g1[i] * rsqrtf(b_v1[i] + EPSBN);
    BR(rr)[i] = comb[rr * CSTR + i] * s + (b_b1[i] - b_m1[i] * s);
  }
  {
    const bool m56 = (lane < 56);
    float acc[4][2];
    #pragma unroll
    for (int rr = 0; rr < 4; ++rr) { acc[rr][0]=acc[rr][1]=0.f; }
    for (int i = 0; i < kN2; i += 4) {
      float4 v[4];
      #pragma unroll
      for (int rr = 0; rr < 4; ++rr) v[rr] = *reinterpret_cast<const float4*>(AR(rr) + i);
      #pragma unroll
      for (int io = 0; io < 4; ++io) {
        const float* wp = e_d3_w + (size_t)(i + io) * 120 + lane;
        float w0 = wp[0];
        float w1 = m56 ? wp[64] : 0.f;
        #pragma unroll
        for (int rr = 0; rr < 4; ++rr) {
          float xv = reinterpret_cast<const float*>(&v[rr])[io];
          acc[rr][0] = fmaf(xv, w0, acc[rr][0]);
          acc[rr][1] = fmaf(xv, w1, acc[rr][1]);
        }
      }
    }
    #pragma unroll
    for (int c = 0; c < 2; ++c) {
      int j = c * 64 + lane;
      if (j < 120) {
        float bs = e_d3_b[j];
        #pragma unroll
        for (int rr = 0; rr < 4; ++rr)
          out[(size_t)(b0 + rr) * kOut + j] = acc[rr][c] + bs;
      }
    }
  }
  __syncthreads();
  {
    float acc[4] = {0.f, 0.f, 0.f, 0.f};
    for (int i = 0; i < kC1; i += 4) {
      float4 v[4];
      #pragma unroll
      for (int rr = 0; rr < 4; ++rr) v[rr] = *reinterpret_cast<const float4*>(BR(rr) + i);
      #pragma unroll
      for (int io = 0; io < 4; ++io) {
        float w0 = b_d1_w[(size_t)(i + io) * 64 + lane];
        #pragma unroll
        for (int rr = 0; rr < 4; ++rr) {
          float xv = reinterpret_cast<const float*>(&v[rr])[io];
          acc[rr] = fmaf(xv, w0, acc[rr]);
        }
      }
    }
    float s  = b_g2[lane] * rsqrtf(b_v2[lane] + EPSBN);
    float t  = b_b2[lane] - b_m2[lane] * s;
    float bs = b_d1_b[lane];
    #pragma unroll
    for (int rr = 0; rr < 4; ++rr)
      AR(rr)[lane] = tanhf(acc[rr] + bs) * s + t;
  }
  __syncthreads();
  {
    const bool m32 = (lane < 32);
    float acc[4] = {0.f, 0.f, 0.f, 0.f};
    for (int i = 0; i < 64; i += 4) {
      float4 v[4];
      #pragma unroll
      for (int rr = 0; rr < 4; ++rr) v[rr] = *reinterpret_cast<const float4*>(AR(rr) + i);
      #pragma unroll
      for (int io = 0; io < 4; ++io) {
        float w0 = m32 ? b_d2_w[(size_t)(i + io) * 32 + lane] : 0.f;
        #pragma unroll
        for (int rr = 0; rr < 4; ++rr) {
          float xv = reinterpret_cast<const float*>(&v[rr])[io];
          acc[rr] = fmaf(xv, w0, acc[rr]);
        }
      }
    }
    if (m32) {
      float bs = b_d2_b[lane];
      #pragma unroll
      for (int rr = 0; rr < 4; ++rr)
        BR(rr)[lane] = tanhf(acc[rr] + bs);
    }
  }
  __syncthreads();
  if (lane < 4) {
    int rr = lane;
    float acc = b_d3_b[0];
    #pragma unroll
    for (int i = 0; i < 32; ++i)
      acc = fmaf(BR(rr)[i], b_d3_w[i], acc);
    out[(size_t)(b0 + rr) * kOut + 120] = 1.f / (1.f + expf(-acc));
  }
  #undef AR
  #undef BR
}

extern "C" void kernel_launch(void* const* d_in, const int* in_sizes, int n_in,
                              void* d_out, int out_size, void* d_ws, size_t ws_size,
                              hipStream_t stream) {
  (void)in_sizes; (void)n_in; (void)out_size;
  const float* p[31];
  for (int i = 0; i < 31; ++i) p[i] = (const float*)d_in[i];
  float* out = (float*)d_out;
  const size_t need = (size_t)BTOT * kC1 * sizeof(float);   // 12.6 MB

  if (ws_size >= need && d_ws != nullptr) {
    float* combined = (float*)d_ws;
    hipLaunchKernelGGL(conv_kernel, dim3(BTOT / 16), dim3(256), 0, stream,
                       p[0], p[1], p[2], combined);
    hipLaunchKernelGGL(mlp_kernel, dim3(BTOT / 32), dim3(256), 0, stream,
                       combined,
                       p[3], p[4], p[5], p[6], p[7], p[8], p[9], p[10], p[11], p[12],
                       p[13], p[14], p[15], p[16], p[17], p[18], p[19], p[20], p[21],
                       p[22], p[23], p[24], p[25], p[26], p[27], p[28], p[29], p[30],
                       out);
  } else {
    hipLaunchKernelGGL(fused_blink_fb, dim3(BTOT / 4), dim3(64), 0, stream,
      p[0], p[1], p[2], p[3], p[4], p[5], p[6], p[7], p[8], p[9],
      p[10], p[11], p[12], p[13], p[14], p[15], p[16], p[17], p[18], p[19],
      p[20], p[21], p[22], p[23], p[24], p[25], p[26], p[27], p[28], p[29], p[30],
      out);
  }
}